// Round 8
// baseline (190.330 us; speedup 1.0000x reference)
//
#include <hip/hip_runtime.h>
#include <hip/hip_cooperative_groups.h>
#include <cstdint>
#include <cstddef>

namespace cg = cooperative_groups;

#define NPT 128
#define CC 1280
#define MID 128

typedef __attribute__((ext_vector_type(8))) short bf16x8;
typedef __attribute__((ext_vector_type(4))) float f32x4;

__device__ __forceinline__ unsigned short f2bf(float f) {
  unsigned u = __builtin_bit_cast(unsigned, f);
  u += 0x7FFFu + ((u >> 16) & 1u);  // RNE
  return (unsigned short)(u >> 16);
}

struct KArgs {
  const float *w2_0, *w2_1, *w2_2, *w2_3;
  unsigned short *W2T0, *W2T1, *W2T2, *W2T3;
  const float* kp;
  const int* subsets;
  int* counts;
  int* plist;
  float* lossm;
  const float* pe;
  const float* w1s;
  const float* b1s;
  float* part;
  unsigned short* H;
  const float *b20, *b21, *b22, *b23;
  float *out0, *out1, *out2, *out3;
};

// ===========================================================================
// Phase A unit 0..127: pe1 MFMA split-K: pe(256x1280)@w1s(1280x512) -> part[4][256][512]
__device__ __forceinline__ void pe1_unit(const KArgs& a, int unit, int tid, char* smem) {
  unsigned short* Asl = (unsigned short*)smem;          // [64 pe-rows][64 k]
  unsigned short* Bsl = (unsigned short*)(smem + 8192); // [64 out-cols][64 k]
  int nt = unit & 7, mt = (unit >> 3) & 3, kz = unit >> 5;
  int n0 = nt * 64, m0 = mt * 64;
  int l = n0 >> 7, m0c = n0 & 127;
  const float* wbase = a.w1s + (size_t)l * CC * MID + m0c;
  int lane = tid & 63;
  int wave = tid >> 6;
  int lr = lane & 15, lk = lane >> 4;
  int choff = (wave & 1) * 32, spoff = (wave >> 1) * 32;
  f32x4 acc00 = {0.f, 0.f, 0.f, 0.f}, acc01 = acc00, acc10 = acc00, acc11 = acc00;
  for (int sub = 0; sub < 5; ++sub) {
    int kc0 = kz * 320 + sub * 64;
    __syncthreads();
    for (int u = tid; u < 512; u += 256) {
      int r = u >> 3, g = u & 7;
      const float* src = a.pe + (size_t)(m0 + r) * CC + kc0 + g * 8;
      float4 v0 = *reinterpret_cast<const float4*>(src);
      float4 v1 = *reinterpret_cast<const float4*>(src + 4);
      uint4 pk;
      pk.x = (unsigned)f2bf(v0.x) | ((unsigned)f2bf(v0.y) << 16);
      pk.y = (unsigned)f2bf(v0.z) | ((unsigned)f2bf(v0.w) << 16);
      pk.z = (unsigned)f2bf(v1.x) | ((unsigned)f2bf(v1.y) << 16);
      pk.w = (unsigned)f2bf(v1.z) | ((unsigned)f2bf(v1.w) << 16);
      *reinterpret_cast<uint4*>(&Asl[r * 64 + ((g ^ (r & 7)) << 3)]) = pk;
    }
    for (int u = tid; u < 512; u += 256) {
      int r = u & 63, gg = u >> 6;
      float vv[8];
#pragma unroll
      for (int j = 0; j < 8; ++j)
        vv[j] = wbase[(size_t)(kc0 + gg * 8 + j) * MID + r];
      uint4 pk;
      pk.x = (unsigned)f2bf(vv[0]) | ((unsigned)f2bf(vv[1]) << 16);
      pk.y = (unsigned)f2bf(vv[2]) | ((unsigned)f2bf(vv[3]) << 16);
      pk.z = (unsigned)f2bf(vv[4]) | ((unsigned)f2bf(vv[5]) << 16);
      pk.w = (unsigned)f2bf(vv[6]) | ((unsigned)f2bf(vv[7]) << 16);
      *reinterpret_cast<uint4*>(&Bsl[r * 64 + ((gg ^ (r & 7)) << 3)]) = pk;
    }
    __syncthreads();
#pragma unroll
    for (int kk = 0; kk < 64; kk += 32) {
      int gbase = (kk >> 3) + lk;
      int r0w = choff + lr, r1w = choff + 16 + lr;
      int r0a = spoff + lr, r1a = spoff + 16 + lr;
      bf16x8 wf0 = *reinterpret_cast<const bf16x8*>(&Bsl[r0w * 64 + ((gbase ^ (r0w & 7)) << 3)]);
      bf16x8 wf1 = *reinterpret_cast<const bf16x8*>(&Bsl[r1w * 64 + ((gbase ^ (r1w & 7)) << 3)]);
      bf16x8 af0 = *reinterpret_cast<const bf16x8*>(&Asl[r0a * 64 + ((gbase ^ (r0a & 7)) << 3)]);
      bf16x8 af1 = *reinterpret_cast<const bf16x8*>(&Asl[r1a * 64 + ((gbase ^ (r1a & 7)) << 3)]);
      acc00 = __builtin_amdgcn_mfma_f32_16x16x32_bf16(wf0, af0, acc00, 0, 0, 0);
      acc01 = __builtin_amdgcn_mfma_f32_16x16x32_bf16(wf0, af1, acc01, 0, 0, 0);
      acc10 = __builtin_amdgcn_mfma_f32_16x16x32_bf16(wf1, af0, acc10, 0, 0, 0);
      acc11 = __builtin_amdgcn_mfma_f32_16x16x32_bf16(wf1, af1, acc11, 0, 0, 0);
    }
  }
  float* pb = a.part + (size_t)kz * 131072;
#define PEPI(ACC, CI, SI)                                                      \
  {                                                                            \
    int spl = spoff + (SI) * 16 + lr;                                          \
    int chl = choff + (CI) * 16 + lk * 4;                                      \
    float4 v = make_float4(ACC[0], ACC[1], ACC[2], ACC[3]);                    \
    *reinterpret_cast<float4*>(&pb[(size_t)(m0 + spl) * 512 + n0 + chl]) = v;  \
  }
  PEPI(acc00, 0, 0)
  PEPI(acc01, 0, 1)
  PEPI(acc10, 1, 0)
  PEPI(acc11, 1, 1)
#undef PEPI
}

// ===========================================================================
// Phase A cheap units c in [0,600): 0-31 binning, 32-471 w2 transpose, 472-599 ones
__device__ __forceinline__ void cheap_unit(const KArgs& a, int c, int tid, char* smem) {
  if (c < 32) {
    int bf = c;
    int* lcnt = (int*)smem;
    for (int i = tid; i < 1024; i += 256) lcnt[i] = 0;
    __syncthreads();
    if (tid < NPT) {
      int p = bf * NPT + tid;
      float kx = a.kp[2 * p], ky = a.kp[2 * p + 1];
      int sub = a.subsets[p];
      if (fminf(kx, ky) >= 0.f && sub != -1) {
        int px = (int)floorf(kx * 32.f);
        px = px < 0 ? 0 : (px > 31 ? 31 : px);
        int py = (int)floorf(ky * 32.f);
        py = py < 0 ? 0 : (py > 31 ? 31 : py);
        int cell = py * 32 + px;
        int slot = atomicAdd(&lcnt[cell], 1);
        if (slot < 32) a.plist[((size_t)bf * 1024 + cell) * 32 + slot] = tid;
      }
    }
    __syncthreads();
    for (int i = tid; i < 1024; i += 256) a.counts[bf * 1024 + i] = lcnt[i];
  } else if (c < 472) {
    float (*ts)[33] = (float(*)[33])smem;
    int local = c - 32;
    const float* w2;
    unsigned short* wt;
    int ch;
    if (local < 40) { w2 = a.w2_0; wt = a.W2T0; ch = 320; }
    else if (local < 120) { w2 = a.w2_1; wt = a.W2T1; ch = 640; local -= 40; }
    else if (local < 280) { w2 = a.w2_2; wt = a.W2T2; ch = 1280; local -= 120; }
    else { w2 = a.w2_3; wt = a.W2T3; ch = 1280; local -= 280; }
    int ctiles = ch >> 5;
    int mt = local / ctiles, ct = local % ctiles;
    int m0 = mt * 32, c0 = ct * 32;
    int i = tid >> 5, j = tid & 31;
#pragma unroll
    for (int r = 0; r < 4; ++r) {
      int m = r * 8 + i;
      ts[m][j] = w2[(size_t)(m0 + m) * ch + c0 + j];
    }
    __syncthreads();
#pragma unroll
    for (int r = 0; r < 4; ++r) {
      int cc = r * 8 + i;
      wt[(size_t)(c0 + cc) * 128 + m0 + j] = f2bf(ts[j][cc]);
    }
  } else {
    int idx = (c - 472) * 256 + tid;
    *reinterpret_cast<float4*>(a.lossm + (size_t)idx * 4) = make_float4(1.f, 1.f, 1.f, 1.f);
  }
}

// ===========================================================================
// Phase B: cells [base, base+n): H[l][cell][m] = bf16(silu(mean+b1)), sums 4 partials.
__device__ __forceinline__ void hid_range(const KArgs& a, int base, int n, int tid,
                                          int* ccache, int* lst) {
  if (tid < n) ccache[tid] = a.counts[base + tid];
  __syncthreads();
  for (int q = 0; q < n; ++q) {
    int c = ccache[q];
    if (c == 0) continue;  // block-uniform
    __syncthreads();
    int cell = base + q;
    int cu = c < 32 ? c : 32;
    if (tid < cu) lst[tid] = a.plist[(size_t)cell * 32 + tid];
    __syncthreads();
    int bat = cell >> 14;
    float invc = 1.f / (float)c;
    float s0 = 0.f, s1 = 0.f;
    for (int i = 0; i < cu; ++i) {
      const float* rp = a.part + (size_t)(bat * NPT + lst[i]) * 512;
      s0 += rp[tid] + rp[131072 + tid] + rp[262144 + tid] + rp[393216 + tid];
      s1 += rp[tid + 256] + rp[131072 + tid + 256] + rp[262144 + tid + 256] +
            rp[393216 + tid + 256];
    }
    float t0 = s0 * invc + a.b1s[tid];
    float t1 = s1 * invc + a.b1s[tid + 256];
    t0 = t0 / (1.f + expf(-t0));
    t1 = t1 / (1.f + expf(-t1));
    int l0 = tid >> 7, m = tid & 127;
    a.H[(size_t)l0 * 4194304 + (size_t)cell * 128 + m] = f2bf(t0);
    a.H[(size_t)(l0 + 2) * 4194304 + (size_t)cell * 128 + m] = f2bf(t1);
  }
}

// ===========================================================================
// Phase C body: MFMA GEMM, 64sp x 64ch tile x 5 ch-iterations.
// D = mfma(af, wf): lane&15 -> channel, (lane>>4)*4+reg -> spatial => float4 stores.
template <int LOGW, int SCALE, int OFF, bool GATED>
__device__ __forceinline__ void mgemm_body(int bx, int byg,
                                           const unsigned short* __restrict__ Hl,
                                           const unsigned short* __restrict__ W2,
                                           const float* __restrict__ b2,
                                           const int* __restrict__ counts,
                                           float* __restrict__ out, int ch,
                                           unsigned short* Asl, unsigned short* Wsl,
                                           float* Ssl, float* Mnl) {
  const int W = 1 << LOGW;
  const int SDIM = 1 << (2 * LOGW);
  int r0 = bx * 64;
  int img = r0 >> (2 * LOGW);
  int tid = threadIdx.x;
  if (GATED) {
    for (int idx = tid; idx < 1024; idx += 256) {
      int r = idx >> 4, g = idx & 15;
      uint4 v = make_uint4(0u, 0u, 0u, 0u);
      if (counts[r0 + r] > 0)
        v = *reinterpret_cast<const uint4*>(Hl + (size_t)(r0 + r) * 128 + g * 8);
      *reinterpret_cast<uint4*>(&Asl[r * 128 + ((g ^ (r & 7)) << 3)]) = v;
    }
    if (tid < 64) {
      float mv = counts[r0 + tid] > 0 ? 1.f : 0.f;
      Ssl[tid] = mv;
      Mnl[tid] = mv;
    }
  } else {
    for (int idx = tid; idx < 1024; idx += 256) {
      int r = idx >> 4, g = idx & 15;
      int cr = r0 + r;
      int sp = cr & (SDIM - 1);
      int y = sp >> LOGW, x = sp & (W - 1);
      int c00 = (cr >> (2 * LOGW)) * 1024 + (SCALE * y + OFF) * 32 + (SCALE * x + OFF);
      int n00 = counts[c00], n01 = counts[c00 + 1];
      int n10 = counts[c00 + 32], n11 = counts[c00 + 33];
      float acc[8] = {};
#define ADDCELL(CELL)                                                      \
      {                                                                    \
        uint4 hv = *reinterpret_cast<const uint4*>(Hl + (size_t)(CELL) * 128 + g * 8); \
        unsigned uu[4] = {hv.x, hv.y, hv.z, hv.w};                         \
        _Pragma("unroll")                                                  \
        for (int qq = 0; qq < 4; ++qq) {                                   \
          acc[2 * qq] += __builtin_bit_cast(float, uu[qq] << 16);          \
          acc[2 * qq + 1] += __builtin_bit_cast(float, uu[qq] & 0xFFFF0000u); \
        }                                                                  \
      }
      if (n00 > 0) ADDCELL(c00)
      if (n01 > 0) ADDCELL(c00 + 1)
      if (n10 > 0) ADDCELL(c00 + 32)
      if (n11 > 0) ADDCELL(c00 + 33)
#undef ADDCELL
      unsigned short pk[8];
#pragma unroll
      for (int qq = 0; qq < 8; ++qq) pk[qq] = f2bf(0.25f * acc[qq]);
      uint4 v;
      v.x = (unsigned)pk[0] | ((unsigned)pk[1] << 16);
      v.y = (unsigned)pk[2] | ((unsigned)pk[3] << 16);
      v.z = (unsigned)pk[4] | ((unsigned)pk[5] << 16);
      v.w = (unsigned)pk[6] | ((unsigned)pk[7] << 16);
      *reinterpret_cast<uint4*>(&Asl[r * 128 + ((g ^ (r & 7)) << 3)]) = v;
    }
    if (tid < 64) {
      int cr = r0 + tid;
      int sp = cr & (SDIM - 1);
      int y = sp >> LOGW, x = sp & (W - 1);
      int ib = (cr >> (2 * LOGW)) * 1024;
      int c00 = ib + (SCALE * y + OFF) * 32 + (SCALE * x + OFF);
      float sm = (counts[c00] > 0 ? 1.f : 0.f) + (counts[c00 + 1] > 0 ? 1.f : 0.f) +
                 (counts[c00 + 32] > 0 ? 1.f : 0.f) + (counts[c00 + 33] > 0 ? 1.f : 0.f);
      Ssl[tid] = 0.25f * sm;
      Mnl[tid] = counts[ib + (SCALE * y) * 32 + SCALE * x] > 0 ? 1.f : 0.f;
    }
  }
  int lane = tid & 63;
  int wave = tid >> 6;
  int lr = lane & 15, lk = lane >> 4;
  int choff = (wave & 1) * 32, spoff = (wave >> 1) * 32;

  for (int it = 0; it < 5; ++it) {
    int k0 = (byg * 5 + it) * 64;
    __syncthreads();
    for (int idx = tid; idx < 1024; idx += 256) {
      int r = idx >> 4, g = idx & 15;
      uint4 v = *reinterpret_cast<const uint4*>(W2 + (size_t)(k0 + r) * 128 + g * 8);
      *reinterpret_cast<uint4*>(&Wsl[r * 128 + ((g ^ (r & 7)) << 3)]) = v;
    }
    __syncthreads();
    f32x4 a00 = {0.f, 0.f, 0.f, 0.f}, a01 = a00, a10 = a00, a11 = a00;
#pragma unroll
    for (int kk = 0; kk < 128; kk += 32) {
      int gbase = (kk >> 3) + lk;
      int r0w = choff + lr, r1w = choff + 16 + lr;
      int r0a = spoff + lr, r1a = spoff + 16 + lr;
      bf16x8 wf0 = *reinterpret_cast<const bf16x8*>(&Wsl[r0w * 128 + ((gbase ^ (r0w & 7)) << 3)]);
      bf16x8 wf1 = *reinterpret_cast<const bf16x8*>(&Wsl[r1w * 128 + ((gbase ^ (r1w & 7)) << 3)]);
      bf16x8 af0 = *reinterpret_cast<const bf16x8*>(&Asl[r0a * 128 + ((gbase ^ (r0a & 7)) << 3)]);
      bf16x8 af1 = *reinterpret_cast<const bf16x8*>(&Asl[r1a * 128 + ((gbase ^ (r1a & 7)) << 3)]);
      a00 = __builtin_amdgcn_mfma_f32_16x16x32_bf16(af0, wf0, a00, 0, 0, 0);
      a01 = __builtin_amdgcn_mfma_f32_16x16x32_bf16(af0, wf1, a01, 0, 0, 0);
      a10 = __builtin_amdgcn_mfma_f32_16x16x32_bf16(af1, wf0, a10, 0, 0, 0);
      a11 = __builtin_amdgcn_mfma_f32_16x16x32_bf16(af1, wf1, a11, 0, 0, 0);
    }
#define EPI(ACC, SI, CI)                                                          \
    {                                                                             \
      int chl = k0 + choff + (CI) * 16 + lr;                                      \
      int spl = spoff + (SI) * 16 + lk * 4;                                       \
      float bv = b2[chl];                                                         \
      float4 o;                                                                   \
      o.x = Mnl[spl + 0] * (ACC[0] + Ssl[spl + 0] * bv);                          \
      o.y = Mnl[spl + 1] * (ACC[1] + Ssl[spl + 1] * bv);                          \
      o.z = Mnl[spl + 2] * (ACC[2] + Ssl[spl + 2] * bv);                          \
      o.w = Mnl[spl + 3] * (ACC[3] + Ssl[spl + 3] * bv);                          \
      int spim = (r0 + spl) & (SDIM - 1);                                         \
      *reinterpret_cast<float4*>(out + (size_t)img * ch * SDIM +                  \
                                 (size_t)chl * SDIM + spim) = o;                  \
    }
    EPI(a00, 0, 0)
    EPI(a01, 0, 1)
    EPI(a10, 1, 0)
    EPI(a11, 1, 1)
#undef EPI
  }
}

__device__ __forceinline__ void mgemm_unit(const KArgs& a, int unit, char* smem) {
  unsigned short* Asl = (unsigned short*)smem;
  unsigned short* Wsl = (unsigned short*)(smem + 16384);
  float* Ssl = (float*)(smem + 32768);
  float* Mnl = (float*)(smem + 33024);
  if (unit < 512) {
    mgemm_body<5, 1, 0, true>(unit, 0, a.H, a.W2T0, a.b20, a.counts, a.out0, 320,
                              Asl, Wsl, Ssl, Mnl);
  } else if (unit < 768) {
    int l = unit - 512;
    mgemm_body<4, 2, 0, false>(l & 127, l >> 7, a.H + 4194304, a.W2T1, a.b21, a.counts,
                               a.out1, 640, Asl, Wsl, Ssl, Mnl);
  } else if (unit < 896) {
    int l = unit - 768;
    mgemm_body<3, 4, 1, false>(l & 31, l >> 5, a.H + 2 * 4194304, a.W2T2, a.b22, a.counts,
                               a.out2, 1280, Asl, Wsl, Ssl, Mnl);
  } else {
    int l = unit - 896;
    mgemm_body<3, 4, 1, false>(l & 31, l >> 5, a.H + 3 * 4194304, a.W2T3, a.b23, a.counts,
                               a.out3, 1280, Asl, Wsl, Ssl, Mnl);
  }
}

// ===========================================================================
// Cooperative fused kernel: grid 512, 2 blocks/CU guaranteed.
__global__ __launch_bounds__(256, 2) void k_fused(KArgs a) {
  __shared__ __align__(16) char smem[33280];
  cg::grid_group grid = cg::this_grid();
  int b = blockIdx.x;
  int tid = threadIdx.x;
  // Phase A
  if (b < 128) {
    pe1_unit(a, b, tid, smem);
  } else {
    int c = b - 128;
    cheap_unit(a, c, tid, smem);
    if (c + 384 < 600) {
      __syncthreads();
      cheap_unit(a, c + 384, tid, smem);
    }
  }
  grid.sync();
  // Phase B
  hid_range(a, b * 64, 64, tid, (int*)smem, (int*)(smem + 256));
  grid.sync();
  // Phase C: 2 tiles per block
  mgemm_unit(a, b, smem);
  __syncthreads();
  mgemm_unit(a, b + 512, smem);
}

// ===========================================================================
// Fallback pipeline (same device code, 3 launches)
__global__ __launch_bounds__(256) void k_preF(KArgs a) {
  __shared__ __align__(16) char smem[17408];
  int b = blockIdx.x;
  if (b < 128) pe1_unit(a, b, threadIdx.x, smem);
  else cheap_unit(a, b - 128, threadIdx.x, smem);
}
__global__ __launch_bounds__(256) void k_hidF(KArgs a) {
  __shared__ int ccache[8];
  __shared__ int lst[32];
  hid_range(a, blockIdx.x * 8, 8, threadIdx.x, ccache, lst);
}
__global__ __launch_bounds__(256) void k_mgemmF(KArgs a) {
  __shared__ __align__(16) char smem[33280];
  mgemm_unit(a, blockIdx.x, smem);
}

// ===========================================================================
extern "C" void kernel_launch(void* const* d_in, const int* in_sizes, int n_in,
                              void* d_out, int out_size, void* d_ws, size_t ws_size,
                              hipStream_t stream) {
  float* out = (float*)d_out;

  float* part = (float*)d_ws;                        // 4*131072 f32
  int* counts = (int*)(part + 524288);               // 32768
  int* plist = counts + 32768;                       // 32768*32
  unsigned short* H = (unsigned short*)(plist + 1048576);  // 4*4194304 bf16
  unsigned short* W2T0 = H + 16777216;
  unsigned short* W2T1 = W2T0 + 40960;
  unsigned short* W2T2 = W2T1 + 81920;
  unsigned short* W2T3 = W2T2 + 163840;

  KArgs ka;
  ka.w2_0 = (const float*)d_in[6];
  ka.w2_1 = (const float*)d_in[8];
  ka.w2_2 = (const float*)d_in[10];
  ka.w2_3 = (const float*)d_in[12];
  ka.W2T0 = W2T0; ka.W2T1 = W2T1; ka.W2T2 = W2T2; ka.W2T3 = W2T3;
  ka.kp = (const float*)d_in[1];
  ka.subsets = (const int*)d_in[2];
  ka.counts = counts;
  ka.plist = plist;
  ka.lossm = out + 20971520;
  ka.pe = (const float*)d_in[0];
  ka.w1s = (const float*)d_in[4];
  ka.b1s = (const float*)d_in[5];
  ka.part = part;
  ka.H = H;
  ka.b20 = (const float*)d_in[7];
  ka.b21 = (const float*)d_in[9];
  ka.b22 = (const float*)d_in[11];
  ka.b23 = (const float*)d_in[13];
  ka.out0 = out;
  ka.out1 = out + 10485760;
  ka.out2 = out + 15728640;
  ka.out3 = out + 18350080;

  // Capture-safe host-side viability check (no statics, recomputed each call).
  int coopAttr = 0, numCU = 0, maxBlk = 0, dev = 0;
  hipGetDevice(&dev);
  hipDeviceGetAttribute(&coopAttr, hipDeviceAttributeCooperativeLaunch, dev);
  hipDeviceGetAttribute(&numCU, hipDeviceAttributeMultiprocessorCount, dev);
  hipOccupancyMaxActiveBlocksPerMultiprocessor(&maxBlk, (const void*)k_fused, 256, 0);

  bool coop_ok = (coopAttr != 0) && ((long)maxBlk * numCU >= 512);
  if (coop_ok) {
    void* kargs[] = {(void*)&ka};
    hipError_t e = hipLaunchCooperativeKernel((const void*)k_fused, dim3(512), dim3(256),
                                              kargs, 0, stream);
    if (e == hipSuccess) return;
    (void)hipGetLastError();  // clear sticky error, fall through to fallback
  }
  k_preF<<<dim3(728), dim3(256), 0, stream>>>(ka);
  k_hidF<<<dim3(4096), dim3(256), 0, stream>>>(ka);
  k_mgemmF<<<dim3(1024), dim3(256), 0, stream>>>(ka);
}

// Round 9
// 63.288 us; speedup vs baseline: 3.0074x; 3.0074x over previous
//
#include <hip/hip_runtime.h>
#include <cstdint>
#include <cstddef>

#define NPT 128
#define CC 1280
#define MID 128

typedef __attribute__((ext_vector_type(8))) short bf16x8;
typedef __attribute__((ext_vector_type(4))) float f32x4;

__device__ __forceinline__ unsigned short f2bf(float f) {
  unsigned u = __builtin_bit_cast(unsigned, f);
  u += 0x7FFFu + ((u >> 16) & 1u);  // RNE
  return (unsigned short)(u >> 16);
}

struct KArgs {
  const float *w2_0, *w2_1, *w2_2, *w2_3;
  unsigned short *W2T0, *W2T1, *W2T2, *W2T3;
  const float* kp;
  const int* subsets;
  int* counts;
  int* plist;
  float* lossm;
  const float* pe;
  const float* w1s;
  const float* b1s;
  float* part;
  unsigned short* H;
  const float *b20, *b21, *b22, *b23;
  float *out0, *out1, *out2, *out3;
};

// ===========================================================================
// K1 unit 0..127: pe1 MFMA split-K: pe(256x1280)@w1s(1280x512) -> part[4][256][512]
__device__ __forceinline__ void pe1_unit(const KArgs& a, int unit, int tid, char* smem) {
  unsigned short* Asl = (unsigned short*)smem;          // [64 pe-rows][64 k]
  unsigned short* Bsl = (unsigned short*)(smem + 8192); // [64 out-cols][64 k]
  int nt = unit & 7, mt = (unit >> 3) & 3, kz = unit >> 5;
  int n0 = nt * 64, m0 = mt * 64;
  int l = n0 >> 7, m0c = n0 & 127;
  const float* wbase = a.w1s + (size_t)l * CC * MID + m0c;
  int lane = tid & 63;
  int wave = tid >> 6;
  int lr = lane & 15, lk = lane >> 4;
  int choff = (wave & 1) * 32, spoff = (wave >> 1) * 32;
  f32x4 acc00 = {0.f, 0.f, 0.f, 0.f}, acc01 = acc00, acc10 = acc00, acc11 = acc00;
  for (int sub = 0; sub < 5; ++sub) {
    int kc0 = kz * 320 + sub * 64;
    __syncthreads();
    for (int u = tid; u < 512; u += 256) {
      int r = u >> 3, g = u & 7;
      const float* src = a.pe + (size_t)(m0 + r) * CC + kc0 + g * 8;
      float4 v0 = *reinterpret_cast<const float4*>(src);
      float4 v1 = *reinterpret_cast<const float4*>(src + 4);
      uint4 pk;
      pk.x = (unsigned)f2bf(v0.x) | ((unsigned)f2bf(v0.y) << 16);
      pk.y = (unsigned)f2bf(v0.z) | ((unsigned)f2bf(v0.w) << 16);
      pk.z = (unsigned)f2bf(v1.x) | ((unsigned)f2bf(v1.y) << 16);
      pk.w = (unsigned)f2bf(v1.z) | ((unsigned)f2bf(v1.w) << 16);
      *reinterpret_cast<uint4*>(&Asl[r * 64 + ((g ^ (r & 7)) << 3)]) = pk;
    }
    for (int u = tid; u < 512; u += 256) {
      int r = u & 63, gg = u >> 6;
      float vv[8];
#pragma unroll
      for (int j = 0; j < 8; ++j)
        vv[j] = wbase[(size_t)(kc0 + gg * 8 + j) * MID + r];
      uint4 pk;
      pk.x = (unsigned)f2bf(vv[0]) | ((unsigned)f2bf(vv[1]) << 16);
      pk.y = (unsigned)f2bf(vv[2]) | ((unsigned)f2bf(vv[3]) << 16);
      pk.z = (unsigned)f2bf(vv[4]) | ((unsigned)f2bf(vv[5]) << 16);
      pk.w = (unsigned)f2bf(vv[6]) | ((unsigned)f2bf(vv[7]) << 16);
      *reinterpret_cast<uint4*>(&Bsl[r * 64 + ((gg ^ (r & 7)) << 3)]) = pk;
    }
    __syncthreads();
#pragma unroll
    for (int kk = 0; kk < 64; kk += 32) {
      int gbase = (kk >> 3) + lk;
      int r0w = choff + lr, r1w = choff + 16 + lr;
      int r0a = spoff + lr, r1a = spoff + 16 + lr;
      bf16x8 wf0 = *reinterpret_cast<const bf16x8*>(&Bsl[r0w * 64 + ((gbase ^ (r0w & 7)) << 3)]);
      bf16x8 wf1 = *reinterpret_cast<const bf16x8*>(&Bsl[r1w * 64 + ((gbase ^ (r1w & 7)) << 3)]);
      bf16x8 af0 = *reinterpret_cast<const bf16x8*>(&Asl[r0a * 64 + ((gbase ^ (r0a & 7)) << 3)]);
      bf16x8 af1 = *reinterpret_cast<const bf16x8*>(&Asl[r1a * 64 + ((gbase ^ (r1a & 7)) << 3)]);
      acc00 = __builtin_amdgcn_mfma_f32_16x16x32_bf16(wf0, af0, acc00, 0, 0, 0);
      acc01 = __builtin_amdgcn_mfma_f32_16x16x32_bf16(wf0, af1, acc01, 0, 0, 0);
      acc10 = __builtin_amdgcn_mfma_f32_16x16x32_bf16(wf1, af0, acc10, 0, 0, 0);
      acc11 = __builtin_amdgcn_mfma_f32_16x16x32_bf16(wf1, af1, acc11, 0, 0, 0);
    }
  }
  float* pb = a.part + (size_t)kz * 131072;
#define PEPI(ACC, CI, SI)                                                      \
  {                                                                            \
    int spl = spoff + (SI) * 16 + lr;                                          \
    int chl = choff + (CI) * 16 + lk * 4;                                      \
    float4 v = make_float4(ACC[0], ACC[1], ACC[2], ACC[3]);                    \
    *reinterpret_cast<float4*>(&pb[(size_t)(m0 + spl) * 512 + n0 + chl]) = v;  \
  }
  PEPI(acc00, 0, 0)
  PEPI(acc01, 0, 1)
  PEPI(acc10, 1, 0)
  PEPI(acc11, 1, 1)
#undef PEPI
}

// ===========================================================================
// K1 cheap units c in [0,600): 0-31 binning, 32-471 w2 transpose, 472-599 ones
__device__ __forceinline__ void cheap_unit(const KArgs& a, int c, int tid, char* smem) {
  if (c < 32) {
    int bf = c;
    int* lcnt = (int*)smem;
    for (int i = tid; i < 1024; i += 256) lcnt[i] = 0;
    __syncthreads();
    if (tid < NPT) {
      int p = bf * NPT + tid;
      float kx = a.kp[2 * p], ky = a.kp[2 * p + 1];
      int sub = a.subsets[p];
      if (fminf(kx, ky) >= 0.f && sub != -1) {
        int px = (int)floorf(kx * 32.f);
        px = px < 0 ? 0 : (px > 31 ? 31 : px);
        int py = (int)floorf(ky * 32.f);
        py = py < 0 ? 0 : (py > 31 ? 31 : py);
        int cell = py * 32 + px;
        int slot = atomicAdd(&lcnt[cell], 1);
        if (slot < 32) a.plist[((size_t)bf * 1024 + cell) * 32 + slot] = tid;
      }
    }
    __syncthreads();
    for (int i = tid; i < 1024; i += 256) a.counts[bf * 1024 + i] = lcnt[i];
  } else if (c < 472) {
    float (*ts)[33] = (float(*)[33])smem;
    int local = c - 32;
    const float* w2;
    unsigned short* wt;
    int ch;
    if (local < 40) { w2 = a.w2_0; wt = a.W2T0; ch = 320; }
    else if (local < 120) { w2 = a.w2_1; wt = a.W2T1; ch = 640; local -= 40; }
    else if (local < 280) { w2 = a.w2_2; wt = a.W2T2; ch = 1280; local -= 120; }
    else { w2 = a.w2_3; wt = a.W2T3; ch = 1280; local -= 280; }
    int ctiles = ch >> 5;
    int mt = local / ctiles, ct = local % ctiles;
    int m0 = mt * 32, c0 = ct * 32;
    int i = tid >> 5, j = tid & 31;
#pragma unroll
    for (int r = 0; r < 4; ++r) {
      int m = r * 8 + i;
      ts[m][j] = w2[(size_t)(m0 + m) * ch + c0 + j];
    }
    __syncthreads();
#pragma unroll
    for (int r = 0; r < 4; ++r) {
      int cc = r * 8 + i;
      wt[(size_t)(c0 + cc) * 128 + m0 + j] = f2bf(ts[j][cc]);
    }
  } else {
    int idx = (c - 472) * 256 + tid;
    *reinterpret_cast<float4*>(a.lossm + (size_t)idx * 4) = make_float4(1.f, 1.f, 1.f, 1.f);
  }
}

// ===========================================================================
// K2: cells [base, base+n): H[l][cell][m] = bf16(silu(mean+b1)), sums 4 partials.
// float2 gather + packed 4B H stores.
__device__ __forceinline__ void hid_range(const KArgs& a, int base, int n, int tid,
                                          int* ccache, int* lst) {
  if (tid < n) ccache[tid] = a.counts[base + tid];
  __syncthreads();
  for (int q = 0; q < n; ++q) {
    int c = ccache[q];
    if (c == 0) continue;  // block-uniform
    __syncthreads();
    int cell = base + q;
    int cu = c < 32 ? c : 32;
    if (tid < cu) lst[tid] = a.plist[(size_t)cell * 32 + tid];
    __syncthreads();
    int bat = cell >> 14;
    float invc = 1.f / (float)c;
    float sx = 0.f, sy = 0.f;
    for (int i = 0; i < cu; ++i) {
      const float2* rp = reinterpret_cast<const float2*>(
          a.part + (size_t)(bat * NPT + lst[i]) * 512);
      float2 v0 = rp[tid];
      float2 v1 = rp[65536 + tid];
      float2 v2 = rp[131072 + tid];
      float2 v3 = rp[196608 + tid];
      sx += v0.x + v1.x + v2.x + v3.x;
      sy += v0.y + v1.y + v2.y + v3.y;
    }
    float2 b = reinterpret_cast<const float2*>(a.b1s)[tid];
    float t0 = sx * invc + b.x;
    float t1 = sy * invc + b.y;
    t0 = t0 / (1.f + expf(-t0));
    t1 = t1 / (1.f + expf(-t1));
    int j0 = tid * 2;
    int l0 = j0 >> 7, m = j0 & 127;
    unsigned pk = (unsigned)f2bf(t0) | ((unsigned)f2bf(t1) << 16);
    *reinterpret_cast<unsigned*>(&a.H[(size_t)l0 * 4194304 + (size_t)cell * 128 + m]) = pk;
  }
}

// ===========================================================================
// K3 body: MFMA GEMM, 64sp x 64ch tile x 5 ch-iterations, W-tile reg prefetch.
// D = mfma(af, wf): lane&15 -> channel, (lane>>4)*4+reg -> spatial => float4 stores.
template <int LOGW, int SCALE, int OFF, bool GATED>
__device__ __forceinline__ void mgemm_body(int bx, int byg,
                                           const unsigned short* __restrict__ Hl,
                                           const unsigned short* __restrict__ W2,
                                           const float* __restrict__ b2,
                                           const int* __restrict__ counts,
                                           float* __restrict__ out, int ch,
                                           unsigned short* Asl, unsigned short* Wsl,
                                           float* Ssl, float* Mnl) {
  const int W = 1 << LOGW;
  const int SDIM = 1 << (2 * LOGW);
  int r0 = bx * 64;
  int img = r0 >> (2 * LOGW);
  int tid = threadIdx.x;
  // ---- W prefetch (tile 0) into registers: thread covers rows r=tid>>2 etc.
  int k0base = byg * 5 * 64;
  int wr = tid >> 2, wg = (tid & 3) << 2;  // 256 threads x 1 uint4 x 4 rounds
  uint4 wreg[4];
#pragma unroll
  for (int rnd = 0; rnd < 4; ++rnd)
    wreg[rnd] = *reinterpret_cast<const uint4*>(
        W2 + (size_t)(k0base + wr + rnd * 64 % 64 + (rnd & 3) * 0) * 128 + 0);
  // (re-issue below properly; placeholder removed by overwrite)
#pragma unroll
  for (int rnd = 0; rnd < 4; ++rnd) {
    int idx = tid + rnd * 256;
    int r = idx >> 4, g = idx & 15;
    wreg[rnd] = *reinterpret_cast<const uint4*>(W2 + (size_t)(k0base + r) * 128 + g * 8);
  }
  // ---- A staging
  if (GATED) {
    for (int idx = tid; idx < 1024; idx += 256) {
      int r = idx >> 4, g = idx & 15;
      uint4 v = make_uint4(0u, 0u, 0u, 0u);
      if (counts[r0 + r] > 0)
        v = *reinterpret_cast<const uint4*>(Hl + (size_t)(r0 + r) * 128 + g * 8);
      *reinterpret_cast<uint4*>(&Asl[r * 128 + ((g ^ (r & 7)) << 3)]) = v;
    }
    if (tid < 64) {
      float mv = counts[r0 + tid] > 0 ? 1.f : 0.f;
      Ssl[tid] = mv;
      Mnl[tid] = mv;
    }
  } else {
    for (int idx = tid; idx < 1024; idx += 256) {
      int r = idx >> 4, g = idx & 15;
      int cr = r0 + r;
      int sp = cr & (SDIM - 1);
      int y = sp >> LOGW, x = sp & (W - 1);
      int c00 = (cr >> (2 * LOGW)) * 1024 + (SCALE * y + OFF) * 32 + (SCALE * x + OFF);
      int n00 = counts[c00], n01 = counts[c00 + 1];
      int n10 = counts[c00 + 32], n11 = counts[c00 + 33];
      float acc[8] = {};
#define ADDCELL(CELL)                                                      \
      {                                                                    \
        uint4 hv = *reinterpret_cast<const uint4*>(Hl + (size_t)(CELL) * 128 + g * 8); \
        unsigned uu[4] = {hv.x, hv.y, hv.z, hv.w};                         \
        _Pragma("unroll")                                                  \
        for (int qq = 0; qq < 4; ++qq) {                                   \
          acc[2 * qq] += __builtin_bit_cast(float, uu[qq] << 16);          \
          acc[2 * qq + 1] += __builtin_bit_cast(float, uu[qq] & 0xFFFF0000u); \
        }                                                                  \
      }
      if (n00 > 0) ADDCELL(c00)
      if (n01 > 0) ADDCELL(c00 + 1)
      if (n10 > 0) ADDCELL(c00 + 32)
      if (n11 > 0) ADDCELL(c00 + 33)
#undef ADDCELL
      unsigned short pk[8];
#pragma unroll
      for (int qq = 0; qq < 8; ++qq) pk[qq] = f2bf(0.25f * acc[qq]);
      uint4 v;
      v.x = (unsigned)pk[0] | ((unsigned)pk[1] << 16);
      v.y = (unsigned)pk[2] | ((unsigned)pk[3] << 16);
      v.z = (unsigned)pk[4] | ((unsigned)pk[5] << 16);
      v.w = (unsigned)pk[6] | ((unsigned)pk[7] << 16);
      *reinterpret_cast<uint4*>(&Asl[r * 128 + ((g ^ (r & 7)) << 3)]) = v;
    }
    if (tid < 64) {
      int cr = r0 + tid;
      int sp = cr & (SDIM - 1);
      int y = sp >> LOGW, x = sp & (W - 1);
      int ib = (cr >> (2 * LOGW)) * 1024;
      int c00 = ib + (SCALE * y + OFF) * 32 + (SCALE * x + OFF);
      float sm = (counts[c00] > 0 ? 1.f : 0.f) + (counts[c00 + 1] > 0 ? 1.f : 0.f) +
                 (counts[c00 + 32] > 0 ? 1.f : 0.f) + (counts[c00 + 33] > 0 ? 1.f : 0.f);
      Ssl[tid] = 0.25f * sm;
      Mnl[tid] = counts[ib + (SCALE * y) * 32 + SCALE * x] > 0 ? 1.f : 0.f;
    }
  }
  int lane = tid & 63;
  int wave = tid >> 6;
  int lr = lane & 15, lk = lane >> 4;
  int choff = (wave & 1) * 32, spoff = (wave >> 1) * 32;

  for (int it = 0; it < 5; ++it) {
    int k0 = k0base + it * 64;
    __syncthreads();
    // write prefetched W tile to LDS
#pragma unroll
    for (int rnd = 0; rnd < 4; ++rnd) {
      int idx = tid + rnd * 256;
      int r = idx >> 4, g = idx & 15;
      *reinterpret_cast<uint4*>(&Wsl[r * 128 + ((g ^ (r & 7)) << 3)]) = wreg[rnd];
    }
    __syncthreads();
    // issue next-tile loads (hide under MFMA + epilogue)
    if (it < 4) {
#pragma unroll
      for (int rnd = 0; rnd < 4; ++rnd) {
        int idx = tid + rnd * 256;
        int r = idx >> 4, g = idx & 15;
        wreg[rnd] = *reinterpret_cast<const uint4*>(
            W2 + (size_t)(k0 + 64 + r) * 128 + g * 8);
      }
    }
    f32x4 a00 = {0.f, 0.f, 0.f, 0.f}, a01 = a00, a10 = a00, a11 = a00;
#pragma unroll
    for (int kk = 0; kk < 128; kk += 32) {
      int gbase = (kk >> 3) + lk;
      int r0w = choff + lr, r1w = choff + 16 + lr;
      int r0a = spoff + lr, r1a = spoff + 16 + lr;
      bf16x8 wf0 = *reinterpret_cast<const bf16x8*>(&Wsl[r0w * 128 + ((gbase ^ (r0w & 7)) << 3)]);
      bf16x8 wf1 = *reinterpret_cast<const bf16x8*>(&Wsl[r1w * 128 + ((gbase ^ (r1w & 7)) << 3)]);
      bf16x8 af0 = *reinterpret_cast<const bf16x8*>(&Asl[r0a * 128 + ((gbase ^ (r0a & 7)) << 3)]);
      bf16x8 af1 = *reinterpret_cast<const bf16x8*>(&Asl[r1a * 128 + ((gbase ^ (r1a & 7)) << 3)]);
      a00 = __builtin_amdgcn_mfma_f32_16x16x32_bf16(af0, wf0, a00, 0, 0, 0);
      a01 = __builtin_amdgcn_mfma_f32_16x16x32_bf16(af0, wf1, a01, 0, 0, 0);
      a10 = __builtin_amdgcn_mfma_f32_16x16x32_bf16(af1, wf0, a10, 0, 0, 0);
      a11 = __builtin_amdgcn_mfma_f32_16x16x32_bf16(af1, wf1, a11, 0, 0, 0);
    }
#define EPI(ACC, SI, CI)                                                          \
    {                                                                             \
      int chl = k0 + choff + (CI) * 16 + lr;                                      \
      int spl = spoff + (SI) * 16 + lk * 4;                                       \
      float bv = b2[chl];                                                         \
      float4 o;                                                                   \
      o.x = Mnl[spl + 0] * (ACC[0] + Ssl[spl + 0] * bv);                          \
      o.y = Mnl[spl + 1] * (ACC[1] + Ssl[spl + 1] * bv);                          \
      o.z = Mnl[spl + 2] * (ACC[2] + Ssl[spl + 2] * bv);                          \
      o.w = Mnl[spl + 3] * (ACC[3] + Ssl[spl + 3] * bv);                          \
      int spim = (r0 + spl) & (SDIM - 1);                                         \
      *reinterpret_cast<float4*>(out + (size_t)img * ch * SDIM +                  \
                                 (size_t)chl * SDIM + spim) = o;                  \
    }
    EPI(a00, 0, 0)
    EPI(a01, 0, 1)
    EPI(a10, 1, 0)
    EPI(a11, 1, 1)
#undef EPI
  }
}

__device__ __forceinline__ void mgemm_unit(const KArgs& a, int unit, char* smem) {
  unsigned short* Asl = (unsigned short*)smem;
  unsigned short* Wsl = (unsigned short*)(smem + 16384);
  float* Ssl = (float*)(smem + 32768);
  float* Mnl = (float*)(smem + 33024);
  if (unit < 512) {
    mgemm_body<5, 1, 0, true>(unit, 0, a.H, a.W2T0, a.b20, a.counts, a.out0, 320,
                              Asl, Wsl, Ssl, Mnl);
  } else if (unit < 768) {
    int l = unit - 512;
    mgemm_body<4, 2, 0, false>(l & 127, l >> 7, a.H + 4194304, a.W2T1, a.b21, a.counts,
                               a.out1, 640, Asl, Wsl, Ssl, Mnl);
  } else if (unit < 896) {
    int l = unit - 768;
    mgemm_body<3, 4, 1, false>(l & 31, l >> 5, a.H + 2 * 4194304, a.W2T2, a.b22, a.counts,
                               a.out2, 1280, Asl, Wsl, Ssl, Mnl);
  } else {
    int l = unit - 896;
    mgemm_body<3, 4, 1, false>(l & 31, l >> 5, a.H + 3 * 4194304, a.W2T3, a.b23, a.counts,
                               a.out3, 1280, Asl, Wsl, Ssl, Mnl);
  }
}

// ===========================================================================
__global__ __launch_bounds__(256) void k_preF(KArgs a) {
  __shared__ __align__(16) char smem[17408];
  int b = blockIdx.x;
  if (b < 128) pe1_unit(a, b, threadIdx.x, smem);
  else cheap_unit(a, b - 128, threadIdx.x, smem);
}
__global__ __launch_bounds__(256) void k_hidF(KArgs a) {
  __shared__ int ccache[8];
  __shared__ int lst[32];
  hid_range(a, blockIdx.x * 8, 8, threadIdx.x, ccache, lst);
}
__global__ __launch_bounds__(256) void k_mgemmF(KArgs a) {
  __shared__ __align__(16) char smem[33280];
  mgemm_unit(a, blockIdx.x, smem);
}

// ===========================================================================
extern "C" void kernel_launch(void* const* d_in, const int* in_sizes, int n_in,
                              void* d_out, int out_size, void* d_ws, size_t ws_size,
                              hipStream_t stream) {
  float* out = (float*)d_out;

  float* part = (float*)d_ws;                        // 4*131072 f32
  int* counts = (int*)(part + 524288);               // 32768
  int* plist = counts + 32768;                       // 32768*32
  unsigned short* H = (unsigned short*)(plist + 1048576);  // 4*4194304 bf16
  unsigned short* W2T0 = H + 16777216;
  unsigned short* W2T1 = W2T0 + 40960;
  unsigned short* W2T2 = W2T1 + 81920;
  unsigned short* W2T3 = W2T2 + 163840;

  KArgs ka;
  ka.w2_0 = (const float*)d_in[6];
  ka.w2_1 = (const float*)d_in[8];
  ka.w2_2 = (const float*)d_in[10];
  ka.w2_3 = (const float*)d_in[12];
  ka.W2T0 = W2T0; ka.W2T1 = W2T1; ka.W2T2 = W2T2; ka.W2T3 = W2T3;
  ka.kp = (const float*)d_in[1];
  ka.subsets = (const int*)d_in[2];
  ka.counts = counts;
  ka.plist = plist;
  ka.lossm = out + 20971520;
  ka.pe = (const float*)d_in[0];
  ka.w1s = (const float*)d_in[4];
  ka.b1s = (const float*)d_in[5];
  ka.part = part;
  ka.H = H;
  ka.b20 = (const float*)d_in[7];
  ka.b21 = (const float*)d_in[9];
  ka.b22 = (const float*)d_in[11];
  ka.b23 = (const float*)d_in[13];
  ka.out0 = out;
  ka.out1 = out + 10485760;
  ka.out2 = out + 15728640;
  ka.out3 = out + 18350080;

  k_preF<<<dim3(728), dim3(256), 0, stream>>>(ka);
  k_hidF<<<dim3(4096), dim3(256), 0, stream>>>(ka);
  k_mgemmF<<<dim3(1024), dim3(256), 0, stream>>>(ka);
}

// Round 10
// 46.417 us; speedup vs baseline: 4.1004x; 1.3635x over previous
//
#include <hip/hip_runtime.h>
#include <cstdint>
#include <cstddef>

#define NPT 128
#define CC 1280
#define MID 128

typedef __attribute__((ext_vector_type(8))) short bf16x8;
typedef __attribute__((ext_vector_type(4))) float f32x4;

__device__ __forceinline__ unsigned short f2bf(float f) {
  unsigned u = __builtin_bit_cast(unsigned, f);
  u += 0x7FFFu + ((u >> 16) & 1u);  // RNE
  return (unsigned short)(u >> 16);
}

struct KArgs {
  const float *w2_0, *w2_1, *w2_2, *w2_3;
  unsigned short *W2T0, *W2T1, *W2T2, *W2T3;
  const float* kp;
  const int* subsets;
  int* counts;
  int* plist;
  float* lossm;
  const float* pe;
  const float* w1s;
  const float* b1s;
  float* part;
  unsigned short* H;
  const float *b20, *b21, *b22, *b23;
  float *out0, *out1, *out2, *out3;
};

// ===========================================================================
// K1 unit 0..127: pe1 MFMA split-K: pe(256x1280)@w1s(1280x512) -> part[4][256][512]
__device__ __forceinline__ void pe1_unit(const KArgs& a, int unit, int tid, char* smem) {
  unsigned short* Asl = (unsigned short*)smem;          // [64 pe-rows][64 k]
  unsigned short* Bsl = (unsigned short*)(smem + 8192); // [64 out-cols][64 k]
  int nt = unit & 7, mt = (unit >> 3) & 3, kz = unit >> 5;
  int n0 = nt * 64, m0 = mt * 64;
  int l = n0 >> 7, m0c = n0 & 127;
  const float* wbase = a.w1s + (size_t)l * CC * MID + m0c;
  int lane = tid & 63;
  int wave = tid >> 6;
  int lr = lane & 15, lk = lane >> 4;
  int choff = (wave & 1) * 32, spoff = (wave >> 1) * 32;
  f32x4 acc00 = {0.f, 0.f, 0.f, 0.f}, acc01 = acc00, acc10 = acc00, acc11 = acc00;
  for (int sub = 0; sub < 5; ++sub) {
    int kc0 = kz * 320 + sub * 64;
    __syncthreads();
    for (int u = tid; u < 512; u += 256) {
      int r = u >> 3, g = u & 7;
      const float* src = a.pe + (size_t)(m0 + r) * CC + kc0 + g * 8;
      float4 v0 = *reinterpret_cast<const float4*>(src);
      float4 v1 = *reinterpret_cast<const float4*>(src + 4);
      uint4 pk;
      pk.x = (unsigned)f2bf(v0.x) | ((unsigned)f2bf(v0.y) << 16);
      pk.y = (unsigned)f2bf(v0.z) | ((unsigned)f2bf(v0.w) << 16);
      pk.z = (unsigned)f2bf(v1.x) | ((unsigned)f2bf(v1.y) << 16);
      pk.w = (unsigned)f2bf(v1.z) | ((unsigned)f2bf(v1.w) << 16);
      *reinterpret_cast<uint4*>(&Asl[r * 64 + ((g ^ (r & 7)) << 3)]) = pk;
    }
    for (int u = tid; u < 512; u += 256) {
      int r = u & 63, gg = u >> 6;
      float vv[8];
#pragma unroll
      for (int j = 0; j < 8; ++j)
        vv[j] = wbase[(size_t)(kc0 + gg * 8 + j) * MID + r];
      uint4 pk;
      pk.x = (unsigned)f2bf(vv[0]) | ((unsigned)f2bf(vv[1]) << 16);
      pk.y = (unsigned)f2bf(vv[2]) | ((unsigned)f2bf(vv[3]) << 16);
      pk.z = (unsigned)f2bf(vv[4]) | ((unsigned)f2bf(vv[5]) << 16);
      pk.w = (unsigned)f2bf(vv[6]) | ((unsigned)f2bf(vv[7]) << 16);
      *reinterpret_cast<uint4*>(&Bsl[r * 64 + ((gg ^ (r & 7)) << 3)]) = pk;
    }
    __syncthreads();
#pragma unroll
    for (int kk = 0; kk < 64; kk += 32) {
      int gbase = (kk >> 3) + lk;
      int r0w = choff + lr, r1w = choff + 16 + lr;
      int r0a = spoff + lr, r1a = spoff + 16 + lr;
      bf16x8 wf0 = *reinterpret_cast<const bf16x8*>(&Bsl[r0w * 64 + ((gbase ^ (r0w & 7)) << 3)]);
      bf16x8 wf1 = *reinterpret_cast<const bf16x8*>(&Bsl[r1w * 64 + ((gbase ^ (r1w & 7)) << 3)]);
      bf16x8 af0 = *reinterpret_cast<const bf16x8*>(&Asl[r0a * 64 + ((gbase ^ (r0a & 7)) << 3)]);
      bf16x8 af1 = *reinterpret_cast<const bf16x8*>(&Asl[r1a * 64 + ((gbase ^ (r1a & 7)) << 3)]);
      acc00 = __builtin_amdgcn_mfma_f32_16x16x32_bf16(wf0, af0, acc00, 0, 0, 0);
      acc01 = __builtin_amdgcn_mfma_f32_16x16x32_bf16(wf0, af1, acc01, 0, 0, 0);
      acc10 = __builtin_amdgcn_mfma_f32_16x16x32_bf16(wf1, af0, acc10, 0, 0, 0);
      acc11 = __builtin_amdgcn_mfma_f32_16x16x32_bf16(wf1, af1, acc11, 0, 0, 0);
    }
  }
  float* pb = a.part + (size_t)kz * 131072;
#define PEPI(ACC, CI, SI)                                                      \
  {                                                                            \
    int spl = spoff + (SI) * 16 + lr;                                          \
    int chl = choff + (CI) * 16 + lk * 4;                                      \
    float4 v = make_float4(ACC[0], ACC[1], ACC[2], ACC[3]);                    \
    *reinterpret_cast<float4*>(&pb[(size_t)(m0 + spl) * 512 + n0 + chl]) = v;  \
  }
  PEPI(acc00, 0, 0)
  PEPI(acc01, 0, 1)
  PEPI(acc10, 1, 0)
  PEPI(acc11, 1, 1)
#undef PEPI
}

// ===========================================================================
// K1 cheap units c in [0,600): 0-31 binning, 32-471 w2 transpose, 472-599 ones
__device__ __forceinline__ void cheap_unit(const KArgs& a, int c, int tid, char* smem) {
  if (c < 32) {
    int bf = c;
    int* lcnt = (int*)smem;
    for (int i = tid; i < 1024; i += 256) lcnt[i] = 0;
    __syncthreads();
    if (tid < NPT) {
      int p = bf * NPT + tid;
      float kx = a.kp[2 * p], ky = a.kp[2 * p + 1];
      int sub = a.subsets[p];
      if (fminf(kx, ky) >= 0.f && sub != -1) {
        int px = (int)floorf(kx * 32.f);
        px = px < 0 ? 0 : (px > 31 ? 31 : px);
        int py = (int)floorf(ky * 32.f);
        py = py < 0 ? 0 : (py > 31 ? 31 : py);
        int cell = py * 32 + px;
        int slot = atomicAdd(&lcnt[cell], 1);
        if (slot < 32) a.plist[((size_t)bf * 1024 + cell) * 32 + slot] = tid;
      }
    }
    __syncthreads();
    for (int i = tid; i < 1024; i += 256) a.counts[bf * 1024 + i] = lcnt[i];
  } else if (c < 472) {
    float (*ts)[33] = (float(*)[33])smem;
    int local = c - 32;
    const float* w2;
    unsigned short* wt;
    int ch;
    if (local < 40) { w2 = a.w2_0; wt = a.W2T0; ch = 320; }
    else if (local < 120) { w2 = a.w2_1; wt = a.W2T1; ch = 640; local -= 40; }
    else if (local < 280) { w2 = a.w2_2; wt = a.W2T2; ch = 1280; local -= 120; }
    else { w2 = a.w2_3; wt = a.W2T3; ch = 1280; local -= 280; }
    int ctiles = ch >> 5;
    int mt = local / ctiles, ct = local % ctiles;
    int m0 = mt * 32, c0 = ct * 32;
    int i = tid >> 5, j = tid & 31;
#pragma unroll
    for (int r = 0; r < 4; ++r) {
      int m = r * 8 + i;
      ts[m][j] = w2[(size_t)(m0 + m) * ch + c0 + j];
    }
    __syncthreads();
#pragma unroll
    for (int r = 0; r < 4; ++r) {
      int cc = r * 8 + i;
      wt[(size_t)(c0 + cc) * 128 + m0 + j] = f2bf(ts[j][cc]);
    }
  } else {
    int idx = (c - 472) * 256 + tid;
    *reinterpret_cast<float4*>(a.lossm + (size_t)idx * 4) = make_float4(1.f, 1.f, 1.f, 1.f);
  }
}

// ===========================================================================
// K2: cells [base, base+n): H[l][cell][m] = bf16(silu(mean+b1)), sums 4 partials.
// float2 gather + packed 4B H stores. Empty cells skipped (H stale, never read).
__device__ __forceinline__ void hid_range(const KArgs& a, int base, int n, int tid,
                                          int* ccache, int* lst) {
  if (tid < n) ccache[tid] = a.counts[base + tid];
  __syncthreads();
  for (int q = 0; q < n; ++q) {
    int c = ccache[q];
    if (c == 0) continue;  // block-uniform
    __syncthreads();
    int cell = base + q;
    int cu = c < 32 ? c : 32;
    if (tid < cu) lst[tid] = a.plist[(size_t)cell * 32 + tid];
    __syncthreads();
    int bat = cell >> 14;
    float invc = 1.f / (float)c;
    float sx = 0.f, sy = 0.f;
    for (int i = 0; i < cu; ++i) {
      const float2* rp = reinterpret_cast<const float2*>(
          a.part + (size_t)(bat * NPT + lst[i]) * 512);
      float2 v0 = rp[tid];
      float2 v1 = rp[65536 + tid];
      float2 v2 = rp[131072 + tid];
      float2 v3 = rp[196608 + tid];
      sx += v0.x + v1.x + v2.x + v3.x;
      sy += v0.y + v1.y + v2.y + v3.y;
    }
    float2 b = reinterpret_cast<const float2*>(a.b1s)[tid];
    float t0 = sx * invc + b.x;
    float t1 = sy * invc + b.y;
    t0 = t0 / (1.f + expf(-t0));
    t1 = t1 / (1.f + expf(-t1));
    int j0 = tid * 2;
    int l0 = j0 >> 7, m = j0 & 127;
    unsigned pk = (unsigned)f2bf(t0) | ((unsigned)f2bf(t1) << 16);
    *reinterpret_cast<unsigned*>(&a.H[(size_t)l0 * 4194304 + (size_t)cell * 128 + m]) = pk;
  }
}

// ===========================================================================
// K3 body (R6-proven): MFMA GEMM, 64sp x 64ch tile x 5 ch-iterations.
// D = mfma(wf, af): lane&15 -> spatial (coalesced scalar stores), reg -> channel.
template <int LOGW, int SCALE, int OFF, bool GATED>
__device__ __forceinline__ void mgemm_body(int bx, int byg,
                                           const unsigned short* __restrict__ Hl,
                                           const unsigned short* __restrict__ W2,
                                           const float* __restrict__ b2,
                                           const int* __restrict__ counts,
                                           float* __restrict__ out, int ch,
                                           unsigned short* Asl, unsigned short* Wsl,
                                           float* Ssl, float* Mnl) {
  const int W = 1 << LOGW;
  const int SDIM = 1 << (2 * LOGW);
  int r0 = bx * 64;
  int img = r0 >> (2 * LOGW);
  int tid = threadIdx.x;
  if (GATED) {
    for (int idx = tid; idx < 1024; idx += 256) {
      int r = idx >> 4, g = idx & 15;
      uint4 v = make_uint4(0u, 0u, 0u, 0u);
      if (counts[r0 + r] > 0)
        v = *reinterpret_cast<const uint4*>(Hl + (size_t)(r0 + r) * 128 + g * 8);
      *reinterpret_cast<uint4*>(&Asl[r * 128 + ((g ^ (r & 7)) << 3)]) = v;
    }
    if (tid < 64) {
      float mv = counts[r0 + tid] > 0 ? 1.f : 0.f;
      Ssl[tid] = mv;
      Mnl[tid] = mv;
    }
  } else {
    for (int idx = tid; idx < 1024; idx += 256) {
      int r = idx >> 4, g = idx & 15;
      int cr = r0 + r;
      int sp = cr & (SDIM - 1);
      int y = sp >> LOGW, x = sp & (W - 1);
      int c00 = (cr >> (2 * LOGW)) * 1024 + (SCALE * y + OFF) * 32 + (SCALE * x + OFF);
      int n00 = counts[c00], n01 = counts[c00 + 1];
      int n10 = counts[c00 + 32], n11 = counts[c00 + 33];
      float acc[8] = {};
#define ADDCELL(CELL)                                                      \
      {                                                                    \
        uint4 hv = *reinterpret_cast<const uint4*>(Hl + (size_t)(CELL) * 128 + g * 8); \
        unsigned uu[4] = {hv.x, hv.y, hv.z, hv.w};                         \
        _Pragma("unroll")                                                  \
        for (int qq = 0; qq < 4; ++qq) {                                   \
          acc[2 * qq] += __builtin_bit_cast(float, uu[qq] << 16);          \
          acc[2 * qq + 1] += __builtin_bit_cast(float, uu[qq] & 0xFFFF0000u); \
        }                                                                  \
      }
      if (n00 > 0) ADDCELL(c00)
      if (n01 > 0) ADDCELL(c00 + 1)
      if (n10 > 0) ADDCELL(c00 + 32)
      if (n11 > 0) ADDCELL(c00 + 33)
#undef ADDCELL
      unsigned short pk[8];
#pragma unroll
      for (int qq = 0; qq < 8; ++qq) pk[qq] = f2bf(0.25f * acc[qq]);
      uint4 v;
      v.x = (unsigned)pk[0] | ((unsigned)pk[1] << 16);
      v.y = (unsigned)pk[2] | ((unsigned)pk[3] << 16);
      v.z = (unsigned)pk[4] | ((unsigned)pk[5] << 16);
      v.w = (unsigned)pk[6] | ((unsigned)pk[7] << 16);
      *reinterpret_cast<uint4*>(&Asl[r * 128 + ((g ^ (r & 7)) << 3)]) = v;
    }
    if (tid < 64) {
      int cr = r0 + tid;
      int sp = cr & (SDIM - 1);
      int y = sp >> LOGW, x = sp & (W - 1);
      int ib = (cr >> (2 * LOGW)) * 1024;
      int c00 = ib + (SCALE * y + OFF) * 32 + (SCALE * x + OFF);
      float sm = (counts[c00] > 0 ? 1.f : 0.f) + (counts[c00 + 1] > 0 ? 1.f : 0.f) +
                 (counts[c00 + 32] > 0 ? 1.f : 0.f) + (counts[c00 + 33] > 0 ? 1.f : 0.f);
      Ssl[tid] = 0.25f * sm;
      Mnl[tid] = counts[ib + (SCALE * y) * 32 + SCALE * x] > 0 ? 1.f : 0.f;
    }
  }
  int lane = tid & 63;
  int wave = tid >> 6;
  int lr = lane & 15, lk = lane >> 4;
  int choff = (wave & 1) * 32, spoff = (wave >> 1) * 32;

  for (int it = 0; it < 5; ++it) {
    int k0 = (byg * 5 + it) * 64;
    __syncthreads();
    for (int idx = tid; idx < 1024; idx += 256) {
      int r = idx >> 4, g = idx & 15;
      uint4 v = *reinterpret_cast<const uint4*>(W2 + (size_t)(k0 + r) * 128 + g * 8);
      *reinterpret_cast<uint4*>(&Wsl[r * 128 + ((g ^ (r & 7)) << 3)]) = v;
    }
    __syncthreads();
    f32x4 a00 = {0.f, 0.f, 0.f, 0.f}, a01 = a00, a10 = a00, a11 = a00;
#pragma unroll
    for (int kk = 0; kk < 128; kk += 32) {
      int gbase = (kk >> 3) + lk;
      int r0w = choff + lr, r1w = choff + 16 + lr;
      int r0a = spoff + lr, r1a = spoff + 16 + lr;
      bf16x8 wf0 = *reinterpret_cast<const bf16x8*>(&Wsl[r0w * 128 + ((gbase ^ (r0w & 7)) << 3)]);
      bf16x8 wf1 = *reinterpret_cast<const bf16x8*>(&Wsl[r1w * 128 + ((gbase ^ (r1w & 7)) << 3)]);
      bf16x8 af0 = *reinterpret_cast<const bf16x8*>(&Asl[r0a * 128 + ((gbase ^ (r0a & 7)) << 3)]);
      bf16x8 af1 = *reinterpret_cast<const bf16x8*>(&Asl[r1a * 128 + ((gbase ^ (r1a & 7)) << 3)]);
      a00 = __builtin_amdgcn_mfma_f32_16x16x32_bf16(wf0, af0, a00, 0, 0, 0);
      a01 = __builtin_amdgcn_mfma_f32_16x16x32_bf16(wf0, af1, a01, 0, 0, 0);
      a10 = __builtin_amdgcn_mfma_f32_16x16x32_bf16(wf1, af0, a10, 0, 0, 0);
      a11 = __builtin_amdgcn_mfma_f32_16x16x32_bf16(wf1, af1, a11, 0, 0, 0);
    }
#define EPI(ACC, CI, SI)                                                          \
    {                                                                             \
      int spl = spoff + (SI) * 16 + lr;                                           \
      int absrow = r0 + spl;                                                      \
      float ss = Ssl[spl], mn = Mnl[spl];                                         \
      float* op = out + (size_t)img * ch * SDIM + (absrow & (SDIM - 1));          \
      _Pragma("unroll")                                                           \
      for (int rr = 0; rr < 4; ++rr) {                                            \
        int chl = k0 + choff + (CI) * 16 + lk * 4 + rr;                           \
        op[(size_t)chl * SDIM] = mn * (ACC[rr] + ss * b2[chl]);                   \
      }                                                                           \
    }
    EPI(a00, 0, 0)
    EPI(a01, 0, 1)
    EPI(a10, 1, 0)
    EPI(a11, 1, 1)
#undef EPI
  }
}

__device__ __forceinline__ void mgemm_unit(const KArgs& a, int unit, char* smem) {
  unsigned short* Asl = (unsigned short*)smem;
  unsigned short* Wsl = (unsigned short*)(smem + 16384);
  float* Ssl = (float*)(smem + 32768);
  float* Mnl = (float*)(smem + 33024);
  if (unit < 512) {
    mgemm_body<5, 1, 0, true>(unit, 0, a.H, a.W2T0, a.b20, a.counts, a.out0, 320,
                              Asl, Wsl, Ssl, Mnl);
  } else if (unit < 768) {
    int l = unit - 512;
    mgemm_body<4, 2, 0, false>(l & 127, l >> 7, a.H + 4194304, a.W2T1, a.b21, a.counts,
                               a.out1, 640, Asl, Wsl, Ssl, Mnl);
  } else if (unit < 896) {
    int l = unit - 768;
    mgemm_body<3, 4, 1, false>(l & 31, l >> 5, a.H + 2 * 4194304, a.W2T2, a.b22, a.counts,
                               a.out2, 1280, Asl, Wsl, Ssl, Mnl);
  } else {
    int l = unit - 896;
    mgemm_body<3, 4, 1, false>(l & 31, l >> 5, a.H + 3 * 4194304, a.W2T3, a.b23, a.counts,
                               a.out3, 1280, Asl, Wsl, Ssl, Mnl);
  }
}

// ===========================================================================
__global__ __launch_bounds__(256) void k_preF(KArgs a) {
  __shared__ __align__(16) char smem[17408];
  int b = blockIdx.x;
  if (b < 128) pe1_unit(a, b, threadIdx.x, smem);
  else cheap_unit(a, b - 128, threadIdx.x, smem);
}
__global__ __launch_bounds__(256) void k_hidF(KArgs a) {
  __shared__ int ccache[8];
  __shared__ int lst[32];
  hid_range(a, blockIdx.x * 8, 8, threadIdx.x, ccache, lst);
}
__global__ __launch_bounds__(256) void k_mgemmF(KArgs a) {
  __shared__ __align__(16) char smem[33280];
  mgemm_unit(a, blockIdx.x, smem);
}

// ===========================================================================
extern "C" void kernel_launch(void* const* d_in, const int* in_sizes, int n_in,
                              void* d_out, int out_size, void* d_ws, size_t ws_size,
                              hipStream_t stream) {
  float* out = (float*)d_out;

  float* part = (float*)d_ws;                        // 4*131072 f32
  int* counts = (int*)(part + 524288);               // 32768
  int* plist = counts + 32768;                       // 32768*32
  unsigned short* H = (unsigned short*)(plist + 1048576);  // 4*4194304 bf16
  unsigned short* W2T0 = H + 16777216;
  unsigned short* W2T1 = W2T0 + 40960;
  unsigned short* W2T2 = W2T1 + 81920;
  unsigned short* W2T3 = W2T2 + 163840;

  KArgs ka;
  ka.w2_0 = (const float*)d_in[6];
  ka.w2_1 = (const float*)d_in[8];
  ka.w2_2 = (const float*)d_in[10];
  ka.w2_3 = (const float*)d_in[12];
  ka.W2T0 = W2T0; ka.W2T1 = W2T1; ka.W2T2 = W2T2; ka.W2T3 = W2T3;
  ka.kp = (const float*)d_in[1];
  ka.subsets = (const int*)d_in[2];
  ka.counts = counts;
  ka.plist = plist;
  ka.lossm = out + 20971520;
  ka.pe = (const float*)d_in[0];
  ka.w1s = (const float*)d_in[4];
  ka.b1s = (const float*)d_in[5];
  ka.part = part;
  ka.H = H;
  ka.b20 = (const float*)d_in[7];
  ka.b21 = (const float*)d_in[9];
  ka.b22 = (const float*)d_in[11];
  ka.b23 = (const float*)d_in[13];
  ka.out0 = out;
  ka.out1 = out + 10485760;
  ka.out2 = out + 15728640;
  ka.out3 = out + 18350080;

  k_preF<<<dim3(728), dim3(256), 0, stream>>>(ka);
  k_hidF<<<dim3(4096), dim3(256), 0, stream>>>(ka);
  k_mgemmF<<<dim3(1024), dim3(256), 0, stream>>>(ka);
}

// Round 11
// 45.058 us; speedup vs baseline: 4.2241x; 1.0302x over previous
//
#include <hip/hip_runtime.h>
#include <cstdint>
#include <cstddef>

#define NPT 128
#define CC 1280
#define MID 128

typedef __attribute__((ext_vector_type(8))) short bf16x8;
typedef __attribute__((ext_vector_type(4))) float f32x4;

__device__ __forceinline__ unsigned short f2bf(float f) {
  unsigned u = __builtin_bit_cast(unsigned, f);
  u += 0x7FFFu + ((u >> 16) & 1u);  // RNE
  return (unsigned short)(u >> 16);
}

struct KArgs {
  const float *w2_0, *w2_1, *w2_2, *w2_3;
  unsigned short *W2T0, *W2T1, *W2T2, *W2T3;
  const float* kp;
  const int* subsets;
  int* counts;
  int* plist;
  float* lossm;
  const float* pe;
  const float* w1s;
  const float* b1s;
  float* part;
  const float *b20, *b21, *b22, *b23;
  float *out0, *out1, *out2, *out3;
};

// ===========================================================================
// K1 unit 0..127: pe1 MFMA split-K: pe(256x1280)@w1s(1280x512) -> part[4][256][512]
__device__ __forceinline__ void pe1_unit(const KArgs& a, int unit, int tid, char* smem) {
  unsigned short* Asl = (unsigned short*)smem;          // [64 pe-rows][64 k]
  unsigned short* Bsl = (unsigned short*)(smem + 8192); // [64 out-cols][64 k]
  int nt = unit & 7, mt = (unit >> 3) & 3, kz = unit >> 5;
  int n0 = nt * 64, m0 = mt * 64;
  int l = n0 >> 7, m0c = n0 & 127;
  const float* wbase = a.w1s + (size_t)l * CC * MID + m0c;
  int lane = tid & 63;
  int wave = tid >> 6;
  int lr = lane & 15, lk = lane >> 4;
  int choff = (wave & 1) * 32, spoff = (wave >> 1) * 32;
  f32x4 acc00 = {0.f, 0.f, 0.f, 0.f}, acc01 = acc00, acc10 = acc00, acc11 = acc00;
  for (int sub = 0; sub < 5; ++sub) {
    int kc0 = kz * 320 + sub * 64;
    __syncthreads();
    for (int u = tid; u < 512; u += 256) {
      int r = u >> 3, g = u & 7;
      const float* src = a.pe + (size_t)(m0 + r) * CC + kc0 + g * 8;
      float4 v0 = *reinterpret_cast<const float4*>(src);
      float4 v1 = *reinterpret_cast<const float4*>(src + 4);
      uint4 pk;
      pk.x = (unsigned)f2bf(v0.x) | ((unsigned)f2bf(v0.y) << 16);
      pk.y = (unsigned)f2bf(v0.z) | ((unsigned)f2bf(v0.w) << 16);
      pk.z = (unsigned)f2bf(v1.x) | ((unsigned)f2bf(v1.y) << 16);
      pk.w = (unsigned)f2bf(v1.z) | ((unsigned)f2bf(v1.w) << 16);
      *reinterpret_cast<uint4*>(&Asl[r * 64 + ((g ^ (r & 7)) << 3)]) = pk;
    }
    for (int u = tid; u < 512; u += 256) {
      int r = u & 63, gg = u >> 6;
      float vv[8];
#pragma unroll
      for (int j = 0; j < 8; ++j)
        vv[j] = wbase[(size_t)(kc0 + gg * 8 + j) * MID + r];
      uint4 pk;
      pk.x = (unsigned)f2bf(vv[0]) | ((unsigned)f2bf(vv[1]) << 16);
      pk.y = (unsigned)f2bf(vv[2]) | ((unsigned)f2bf(vv[3]) << 16);
      pk.z = (unsigned)f2bf(vv[4]) | ((unsigned)f2bf(vv[5]) << 16);
      pk.w = (unsigned)f2bf(vv[6]) | ((unsigned)f2bf(vv[7]) << 16);
      *reinterpret_cast<uint4*>(&Bsl[r * 64 + ((gg ^ (r & 7)) << 3)]) = pk;
    }
    __syncthreads();
#pragma unroll
    for (int kk = 0; kk < 64; kk += 32) {
      int gbase = (kk >> 3) + lk;
      int r0w = choff + lr, r1w = choff + 16 + lr;
      int r0a = spoff + lr, r1a = spoff + 16 + lr;
      bf16x8 wf0 = *reinterpret_cast<const bf16x8*>(&Bsl[r0w * 64 + ((gbase ^ (r0w & 7)) << 3)]);
      bf16x8 wf1 = *reinterpret_cast<const bf16x8*>(&Bsl[r1w * 64 + ((gbase ^ (r1w & 7)) << 3)]);
      bf16x8 af0 = *reinterpret_cast<const bf16x8*>(&Asl[r0a * 64 + ((gbase ^ (r0a & 7)) << 3)]);
      bf16x8 af1 = *reinterpret_cast<const bf16x8*>(&Asl[r1a * 64 + ((gbase ^ (r1a & 7)) << 3)]);
      acc00 = __builtin_amdgcn_mfma_f32_16x16x32_bf16(wf0, af0, acc00, 0, 0, 0);
      acc01 = __builtin_amdgcn_mfma_f32_16x16x32_bf16(wf0, af1, acc01, 0, 0, 0);
      acc10 = __builtin_amdgcn_mfma_f32_16x16x32_bf16(wf1, af0, acc10, 0, 0, 0);
      acc11 = __builtin_amdgcn_mfma_f32_16x16x32_bf16(wf1, af1, acc11, 0, 0, 0);
    }
  }
  float* pb = a.part + (size_t)kz * 131072;
#define PEPI(ACC, CI, SI)                                                      \
  {                                                                            \
    int spl = spoff + (SI) * 16 + lr;                                          \
    int chl = choff + (CI) * 16 + lk * 4;                                      \
    float4 v = make_float4(ACC[0], ACC[1], ACC[2], ACC[3]);                    \
    *reinterpret_cast<float4*>(&pb[(size_t)(m0 + spl) * 512 + n0 + chl]) = v;  \
  }
  PEPI(acc00, 0, 0)
  PEPI(acc01, 0, 1)
  PEPI(acc10, 1, 0)
  PEPI(acc11, 1, 1)
#undef PEPI
}

// ===========================================================================
// K1 cheap units c in [0,600): 0-31 binning, 32-471 w2 transpose, 472-599 ones
__device__ __forceinline__ void cheap_unit(const KArgs& a, int c, int tid, char* smem) {
  if (c < 32) {
    int bf = c;
    int* lcnt = (int*)smem;
    for (int i = tid; i < 1024; i += 256) lcnt[i] = 0;
    __syncthreads();
    if (tid < NPT) {
      int p = bf * NPT + tid;
      float kx = a.kp[2 * p], ky = a.kp[2 * p + 1];
      int sub = a.subsets[p];
      if (fminf(kx, ky) >= 0.f && sub != -1) {
        int px = (int)floorf(kx * 32.f);
        px = px < 0 ? 0 : (px > 31 ? 31 : px);
        int py = (int)floorf(ky * 32.f);
        py = py < 0 ? 0 : (py > 31 ? 31 : py);
        int cell = py * 32 + px;
        int slot = atomicAdd(&lcnt[cell], 1);
        if (slot < 32) a.plist[((size_t)bf * 1024 + cell) * 32 + slot] = tid;
      }
    }
    __syncthreads();
    for (int i = tid; i < 1024; i += 256) a.counts[bf * 1024 + i] = lcnt[i];
  } else if (c < 472) {
    float (*ts)[33] = (float(*)[33])smem;
    int local = c - 32;
    const float* w2;
    unsigned short* wt;
    int ch;
    if (local < 40) { w2 = a.w2_0; wt = a.W2T0; ch = 320; }
    else if (local < 120) { w2 = a.w2_1; wt = a.W2T1; ch = 640; local -= 40; }
    else if (local < 280) { w2 = a.w2_2; wt = a.W2T2; ch = 1280; local -= 120; }
    else { w2 = a.w2_3; wt = a.W2T3; ch = 1280; local -= 280; }
    int ctiles = ch >> 5;
    int mt = local / ctiles, ct = local % ctiles;
    int m0 = mt * 32, c0 = ct * 32;
    int i = tid >> 5, j = tid & 31;
#pragma unroll
    for (int r = 0; r < 4; ++r) {
      int m = r * 8 + i;
      ts[m][j] = w2[(size_t)(m0 + m) * ch + c0 + j];
    }
    __syncthreads();
#pragma unroll
    for (int r = 0; r < 4; ++r) {
      int cc = r * 8 + i;
      wt[(size_t)(c0 + cc) * 128 + m0 + j] = f2bf(ts[j][cc]);
    }
  } else {
    int idx = (c - 472) * 256 + tid;
    *reinterpret_cast<float4*>(a.lossm + (size_t)idx * 4) = make_float4(1.f, 1.f, 1.f, 1.f);
  }
}

// ===========================================================================
// K2 body: fused hid + MFMA GEMM, 64sp x 64ch tile x 5 ch-iterations.
// A-staging gathers part slices per cell, applies mean+b1+silu (f32), packs bf16.
// D = mfma(wf, af): lane&15 -> spatial (coalesced scalar stores), reg -> channel.
template <int LOGW, int SCALE, int OFF, bool GATED>
__device__ __forceinline__ void mgemm_body(int bx, int byg, int lvl,
                                           const float* __restrict__ part,
                                           const int* __restrict__ counts,
                                           const int* __restrict__ plist,
                                           const float* __restrict__ b1s,
                                           const unsigned short* __restrict__ W2,
                                           const float* __restrict__ b2,
                                           float* __restrict__ out, int ch,
                                           unsigned short* Asl, unsigned short* Wsl,
                                           float* Ssl, float* Mnl) {
  const int W = 1 << LOGW;
  const int SDIM = 1 << (2 * LOGW);
  int r0 = bx * 64;
  int img = r0 >> (2 * LOGW);
  int tid = threadIdx.x;

  // ---- A staging with fused hid: 1024 (row, granule) units over 4 rounds
  for (int idx = tid; idx < 1024; idx += 256) {
    int r = idx >> 4, g = idx & 15;
    int cr = r0 + r;
    const float* b1p = b1s + lvl * 128 + g * 8;
    float b1v[8];
#pragma unroll
    for (int j = 0; j < 8; ++j) b1v[j] = b1p[j];
    int c00;
    if (GATED) {
      c00 = cr;
    } else {
      int sp = cr & (SDIM - 1);
      int y = sp >> LOGW, x = sp & (W - 1);
      c00 = (cr >> (2 * LOGW)) * 1024 + (SCALE * y + OFF) * 32 + (SCALE * x + OFF);
    }
    float a8[8] = {};
#pragma unroll
    for (int cc = 0; cc < (GATED ? 1 : 4); ++cc) {
      int cell = c00 + (cc & 1) + (cc >> 1) * 32;
      int cnt = counts[cell];
      if (cnt > 0) {
        int cu = cnt < 32 ? cnt : 32;
        int bat = cell >> 14;
        float c8[8] = {};
        for (int i = 0; i < cu; ++i) {
          int p = plist[(size_t)cell * 32 + i];
          const float* rp = part + (size_t)(bat * NPT + p) * 512 + lvl * 128 + g * 8;
#pragma unroll
          for (int z = 0; z < 4; ++z) {
            float4 v0 = *reinterpret_cast<const float4*>(rp + z * 131072);
            float4 v1 = *reinterpret_cast<const float4*>(rp + z * 131072 + 4);
            c8[0] += v0.x; c8[1] += v0.y; c8[2] += v0.z; c8[3] += v0.w;
            c8[4] += v1.x; c8[5] += v1.y; c8[6] += v1.z; c8[7] += v1.w;
          }
        }
        float invc = 1.f / (float)cnt;
#pragma unroll
        for (int j = 0; j < 8; ++j) {
          float t = c8[j] * invc + b1v[j];
          a8[j] += t / (1.f + expf(-t));
        }
      }
    }
    const float sc = GATED ? 1.f : 0.25f;
    unsigned short pk[8];
#pragma unroll
    for (int j = 0; j < 8; ++j) pk[j] = f2bf(sc * a8[j]);
    uint4 v;
    v.x = (unsigned)pk[0] | ((unsigned)pk[1] << 16);
    v.y = (unsigned)pk[2] | ((unsigned)pk[3] << 16);
    v.z = (unsigned)pk[4] | ((unsigned)pk[5] << 16);
    v.w = (unsigned)pk[6] | ((unsigned)pk[7] << 16);
    *reinterpret_cast<uint4*>(&Asl[r * 128 + ((g ^ (r & 7)) << 3)]) = v;
  }
  // ---- per-row mask terms
  if (tid < 64) {
    int cr = r0 + tid;
    if (GATED) {
      float mv = counts[cr] > 0 ? 1.f : 0.f;
      Ssl[tid] = mv;
      Mnl[tid] = mv;
    } else {
      int sp = cr & (SDIM - 1);
      int y = sp >> LOGW, x = sp & (W - 1);
      int ib = (cr >> (2 * LOGW)) * 1024;
      int c00 = ib + (SCALE * y + OFF) * 32 + (SCALE * x + OFF);
      float sm = (counts[c00] > 0 ? 1.f : 0.f) + (counts[c00 + 1] > 0 ? 1.f : 0.f) +
                 (counts[c00 + 32] > 0 ? 1.f : 0.f) + (counts[c00 + 33] > 0 ? 1.f : 0.f);
      Ssl[tid] = 0.25f * sm;
      Mnl[tid] = counts[ib + (SCALE * y) * 32 + SCALE * x] > 0 ? 1.f : 0.f;
    }
  }
  int lane = tid & 63;
  int wave = tid >> 6;
  int lr = lane & 15, lk = lane >> 4;
  int choff = (wave & 1) * 32, spoff = (wave >> 1) * 32;

  for (int it = 0; it < 5; ++it) {
    int k0 = (byg * 5 + it) * 64;
    __syncthreads();
    for (int idx = tid; idx < 1024; idx += 256) {
      int r = idx >> 4, g = idx & 15;
      uint4 v = *reinterpret_cast<const uint4*>(W2 + (size_t)(k0 + r) * 128 + g * 8);
      *reinterpret_cast<uint4*>(&Wsl[r * 128 + ((g ^ (r & 7)) << 3)]) = v;
    }
    __syncthreads();
    f32x4 a00 = {0.f, 0.f, 0.f, 0.f}, a01 = a00, a10 = a00, a11 = a00;
#pragma unroll
    for (int kk = 0; kk < 128; kk += 32) {
      int gbase = (kk >> 3) + lk;
      int r0w = choff + lr, r1w = choff + 16 + lr;
      int r0a = spoff + lr, r1a = spoff + 16 + lr;
      bf16x8 wf0 = *reinterpret_cast<const bf16x8*>(&Wsl[r0w * 128 + ((gbase ^ (r0w & 7)) << 3)]);
      bf16x8 wf1 = *reinterpret_cast<const bf16x8*>(&Wsl[r1w * 128 + ((gbase ^ (r1w & 7)) << 3)]);
      bf16x8 af0 = *reinterpret_cast<const bf16x8*>(&Asl[r0a * 128 + ((gbase ^ (r0a & 7)) << 3)]);
      bf16x8 af1 = *reinterpret_cast<const bf16x8*>(&Asl[r1a * 128 + ((gbase ^ (r1a & 7)) << 3)]);
      a00 = __builtin_amdgcn_mfma_f32_16x16x32_bf16(wf0, af0, a00, 0, 0, 0);
      a01 = __builtin_amdgcn_mfma_f32_16x16x32_bf16(wf0, af1, a01, 0, 0, 0);
      a10 = __builtin_amdgcn_mfma_f32_16x16x32_bf16(wf1, af0, a10, 0, 0, 0);
      a11 = __builtin_amdgcn_mfma_f32_16x16x32_bf16(wf1, af1, a11, 0, 0, 0);
    }
#define EPI(ACC, CI, SI)                                                          \
    {                                                                             \
      int spl = spoff + (SI) * 16 + lr;                                           \
      int absrow = r0 + spl;                                                      \
      float ss = Ssl[spl], mn = Mnl[spl];                                         \
      float* op = out + (size_t)img * ch * SDIM + (absrow & (SDIM - 1));          \
      _Pragma("unroll")                                                           \
      for (int rr = 0; rr < 4; ++rr) {                                            \
        int chl = k0 + choff + (CI) * 16 + lk * 4 + rr;                           \
        op[(size_t)chl * SDIM] = mn * (ACC[rr] + ss * b2[chl]);                   \
      }                                                                           \
    }
    EPI(a00, 0, 0)
    EPI(a01, 0, 1)
    EPI(a10, 1, 0)
    EPI(a11, 1, 1)
#undef EPI
  }
}

__device__ __forceinline__ void mgemm_unit(const KArgs& a, int unit, char* smem) {
  unsigned short* Asl = (unsigned short*)smem;
  unsigned short* Wsl = (unsigned short*)(smem + 16384);
  float* Ssl = (float*)(smem + 32768);
  float* Mnl = (float*)(smem + 33024);
  if (unit < 512) {
    mgemm_body<5, 1, 0, true>(unit, 0, 0, a.part, a.counts, a.plist, a.b1s,
                              a.W2T0, a.b20, a.out0, 320, Asl, Wsl, Ssl, Mnl);
  } else if (unit < 768) {
    int l = unit - 512;
    mgemm_body<4, 2, 0, false>(l & 127, l >> 7, 1, a.part, a.counts, a.plist, a.b1s,
                               a.W2T1, a.b21, a.out1, 640, Asl, Wsl, Ssl, Mnl);
  } else if (unit < 896) {
    int l = unit - 768;
    mgemm_body<3, 4, 1, false>(l & 31, l >> 5, 2, a.part, a.counts, a.plist, a.b1s,
                               a.W2T2, a.b22, a.out2, 1280, Asl, Wsl, Ssl, Mnl);
  } else {
    int l = unit - 896;
    mgemm_body<3, 4, 1, false>(l & 31, l >> 5, 3, a.part, a.counts, a.plist, a.b1s,
                               a.W2T3, a.b23, a.out3, 1280, Asl, Wsl, Ssl, Mnl);
  }
}

// ===========================================================================
__global__ __launch_bounds__(256) void k_preF(KArgs a) {
  __shared__ __align__(16) char smem[17408];
  int b = blockIdx.x;
  if (b < 128) pe1_unit(a, b, threadIdx.x, smem);
  else cheap_unit(a, b - 128, threadIdx.x, smem);
}
__global__ __launch_bounds__(256) void k_mgemmF(KArgs a) {
  __shared__ __align__(16) char smem[33280];
  mgemm_unit(a, blockIdx.x, smem);
}

// ===========================================================================
extern "C" void kernel_launch(void* const* d_in, const int* in_sizes, int n_in,
                              void* d_out, int out_size, void* d_ws, size_t ws_size,
                              hipStream_t stream) {
  float* out = (float*)d_out;

  float* part = (float*)d_ws;                        // 4*131072 f32
  int* counts = (int*)(part + 524288);               // 32768
  int* plist = counts + 32768;                       // 32768*32
  unsigned short* W2T0 = (unsigned short*)(plist + 1048576);
  unsigned short* W2T1 = W2T0 + 40960;
  unsigned short* W2T2 = W2T1 + 81920;
  unsigned short* W2T3 = W2T2 + 163840;

  KArgs ka;
  ka.w2_0 = (const float*)d_in[6];
  ka.w2_1 = (const float*)d_in[8];
  ka.w2_2 = (const float*)d_in[10];
  ka.w2_3 = (const float*)d_in[12];
  ka.W2T0 = W2T0; ka.W2T1 = W2T1; ka.W2T2 = W2T2; ka.W2T3 = W2T3;
  ka.kp = (const float*)d_in[1];
  ka.subsets = (const int*)d_in[2];
  ka.counts = counts;
  ka.plist = plist;
  ka.lossm = out + 20971520;
  ka.pe = (const float*)d_in[0];
  ka.w1s = (const float*)d_in[4];
  ka.b1s = (const float*)d_in[5];
  ka.part = part;
  ka.b20 = (const float*)d_in[7];
  ka.b21 = (const float*)d_in[9];
  ka.b22 = (const float*)d_in[11];
  ka.b23 = (const float*)d_in[13];
  ka.out0 = out;
  ka.out1 = out + 10485760;
  ka.out2 = out + 15728640;
  ka.out3 = out + 18350080;

  k_preF<<<dim3(728), dim3(256), 0, stream>>>(ka);
  k_mgemmF<<<dim3(1024), dim3(256), 0, stream>>>(ka);
}